// Round 7
// baseline (277.929 us; speedup 1.0000x reference)
//
#include <hip/hip_runtime.h>

typedef unsigned short u16;
typedef unsigned int u32;
typedef __bf16 bf16x8 __attribute__((ext_vector_type(8)));
typedef float f32x4 __attribute__((ext_vector_type(4)));
typedef u16 u16x4 __attribute__((ext_vector_type(4)));
typedef __attribute__((address_space(1))) void* as1_t;
typedef __attribute__((address_space(3))) void* as3_t;

#define LOG2E 1.4426950408889634f
#define MFMA(a,b,c) __builtin_amdgcn_mfma_f32_16x16x32_bf16(a,b,c,0,0,0)

__device__ __forceinline__ u16 f2bf(float f){
  u32 u = __float_as_uint(f);
  return (u16)((u + 0x7FFFu + ((u >> 16) & 1u)) >> 16);
}
__device__ __forceinline__ float bf2f(u16 x){
  return __uint_as_float(((u32)x) << 16);
}
#if __has_builtin(__builtin_amdgcn_cvt_pk_bf16_f32)
__device__ __forceinline__ u16x4 pk4(float a, float b, float c, float d){
  auto lo = __builtin_amdgcn_cvt_pk_bf16_f32(a,b);
  auto hi = __builtin_amdgcn_cvt_pk_bf16_f32(c,d);
  union { u16x4 v; u32 w[2]; } u;
  u.w[0] = __builtin_bit_cast(u32, lo);
  u.w[1] = __builtin_bit_cast(u32, hi);
  return u.v;
}
#else
__device__ __forceinline__ u16x4 pk4(float a, float b, float c, float d){
  u16x4 r = { f2bf(a), f2bf(b), f2bf(c), f2bf(d) };
  return r;
}
#endif
__device__ __forceinline__ void gld16(const u16* gp, u16* lp){
  __builtin_amdgcn_global_load_lds((as1_t)(u16*)gp, (as3_t)lp, 16, 0, 0);
}

// ---------------- prep: cast both inputs + all 5 weight transposes, ONE launch ----------------
__global__ void prep_kernel(const float* __restrict__ vis, u16* __restrict__ vis16,
                            const float* __restrict__ txt, u16* __restrict__ txt16,
                            const float* __restrict__ Wq, const float* __restrict__ Wk,
                            const float* __restrict__ Wv, const float* __restrict__ Wo,
                            u16* __restrict__ T0, u16* __restrict__ T1,
                            u16* __restrict__ T2, u16* __restrict__ T3,
                            u16* __restrict__ T4){
  int bid = blockIdx.x;
  if(bid < 8192){
    const float* src = (bid < 4096) ? vis : txt;
    u16* dst = (bid < 4096) ? vis16 : txt16;
    int idx = ((bid & 4095)*256 + threadIdx.x)*4;
    float4 v = *(const float4*)(src + idx);
    *(u16x4*)(dst + idx) = pk4(v.x, v.y, v.z, v.w);
    return;
  }
  int rr = bid - 8192;
  int wi = rr >> 8, tile = rr & 255;
  const float* W; u16* WT;
  switch(wi){
    case 0: W = Wq; WT = T0; break;
    case 1: W = Wv; WT = T1; break;
    case 2: W = Wk; WT = T2; break;
    case 3: W = Wv; WT = T3; break;
    default: W = Wo; WT = T4; break;
  }
  __shared__ u16 t[64][65];
  int bn = (tile & 15)*64, bk = (tile >> 4)*64;
  int c = threadIdx.x & 63, r0 = threadIdx.x >> 6;
  #pragma unroll
  for(int j=0;j<64;j+=4){
    int r = r0 + j;
    t[r][c] = f2bf(W[(bk + r)*1024 + bn + c]);
  }
  __syncthreads();
  #pragma unroll
  for(int j=0;j<64;j+=4){
    int r = r0 + j;
    WT[(bn + r)*1024 + bk + c] = t[c][r];
  }
}

// ---------------- merged projection GEMM: 128x128 tile, BK=64, DOUBLE-BUFFERED ----------------
// z=0: vis->[Q | V2^T], z=1: txt->[K | V^T]
// n<1024 -> Cn [b][h][s][d]; n>=1024 -> Ct [b][h][d][s] (transposed, u16x4 stores)
__global__ __launch_bounds__(256, 2)
void proj_gemm_kernel(const u16* __restrict__ Avis, const u16* __restrict__ Atxt,
                      const u16* __restrict__ Wvis, const u16* __restrict__ Wtxt,
                      u16* __restrict__ Qb, u16* __restrict__ V2t,
                      u16* __restrict__ Kb, u16* __restrict__ Vt)
{
  const u16 *A, *Bt; u16 *Cn, *Ct;
  if(blockIdx.z == 0){ A = Avis; Bt = Wvis; Cn = Qb; Ct = V2t; }
  else               { A = Atxt; Bt = Wtxt; Cn = Kb; Ct = Vt;  }
  __shared__ u16 lds[32768];     // 2 x (A[c8][128][8] + B[c8][128][8]) = 64 KB
  u16* b0 = lds; u16* b1 = lds + 16384;
  const int tid = threadIdx.x, w = tid >> 6, lane = tid & 63;
  const int quad = lane >> 4, cl = lane & 15;
  const int bm = blockIdx.y*128, bn = blockIdx.x*128;
  const int wm = (w >> 1)*64, wn = (w & 1)*64;
  f32x4 acc[4][4];
  #pragma unroll
  for(int a=0;a<4;a++)
    #pragma unroll
    for(int b=0;b<4;b++){ f32x4 z = {0.f,0.f,0.f,0.f}; acc[a][b] = z; }

  auto stage = [&](u16* buf, int k0){
    #pragma unroll
    for(int i=0;i<4;i++){
      int slot = (w*4+i)*64 + lane;
      int c = slot >> 7, r = slot & 127;
      gld16(A  + (size_t)(bm + r)*1024 + k0 + c*8, buf + (w*4+i)*512);
      gld16(Bt + (size_t)(bn + r)*1024 + k0 + c*8, buf + 8192 + (w*4+i)*512);
    }
  };
  auto compute = [&](const u16* buf){
    const u16* Al = buf; const u16* Bl = buf + 8192;
    bf16x8 af[4][2], bfv[4][2];
    #pragma unroll
    for(int mt=0;mt<4;mt++)
      #pragma unroll
      for(int kc=0;kc<2;kc++)
        af[mt][kc] = *(const bf16x8*)(Al + (((kc*4+quad)*128) + wm + mt*16 + cl)*8);
    #pragma unroll
    for(int nt=0;nt<4;nt++)
      #pragma unroll
      for(int kc=0;kc<2;kc++)
        bfv[nt][kc] = *(const bf16x8*)(Bl + (((kc*4+quad)*128) + wn + nt*16 + cl)*8);
    #pragma unroll
    for(int mt=0;mt<4;mt++)
      #pragma unroll
      for(int nt=0;nt<4;nt++)
        #pragma unroll
        for(int kc=0;kc<2;kc++)
          acc[mt][nt] = MFMA(af[mt][kc], bfv[nt][kc], acc[mt][nt]);
  };

  stage(b0, 0);
  #pragma unroll 1
  for(int it=0; it<16; it+=2){
    __syncthreads();                       // drains b0 loads (overlapped w/ prev compute)
    if(it+1 < 16) stage(b1, (it+1)*64);    // prefetch next, in flight during compute
    compute(b0);
    __syncthreads();                       // drains b1 loads
    if(it+2 < 16) stage(b0, (it+2)*64);
    compute(b1);
  }
  #pragma unroll
  for(int mt=0;mt<4;mt++)
    #pragma unroll
    for(int nt=0;nt<4;nt++){
      int n = bn + wn + nt*16 + cl;
      int m0 = bm + wm + mt*16 + quad*4;
      if(n < 1024){
        int h = n >> 6, d = n & 63;
        #pragma unroll
        for(int i=0;i<4;i++){
          int m = m0 + i;
          int b = m >> 10, s = m & 1023;
          Cn[(((size_t)(b*16 + h)*1024 + s) << 6) + d] = f2bf(acc[mt][nt][i]);
        }
      } else {
        int nn = n - 1024, h = nn >> 6, d = nn & 63;
        int b = m0 >> 10, s = m0 & 1023;
        *(u16x4*)(Ct + (((size_t)(b*16 + h)*64 + d) << 10) + s) =
            pk4(acc[mt][nt][0], acc[mt][nt][1], acc[mt][nt][2], acc[mt][nt][3]);
      }
    }
}

// ---------------- output GEMM: out[8192 x 1024] f32, 128x128, BK=64, DOUBLE-BUFFERED --------
__global__ __launch_bounds__(256, 2)
void out_gemm_kernel(const u16* __restrict__ A, const u16* __restrict__ Bt,
                     float* __restrict__ Cf)
{
  __shared__ u16 lds[32768];
  u16* b0 = lds; u16* b1 = lds + 16384;
  const int tid = threadIdx.x, w = tid >> 6, lane = tid & 63;
  const int quad = lane >> 4, cl = lane & 15;
  const int bm = blockIdx.y*128, bn = blockIdx.x*128;
  const int wm = (w >> 1)*64, wn = (w & 1)*64;
  f32x4 acc[4][4];
  #pragma unroll
  for(int a=0;a<4;a++)
    #pragma unroll
    for(int b=0;b<4;b++){ f32x4 z = {0.f,0.f,0.f,0.f}; acc[a][b] = z; }

  auto stage = [&](u16* buf, int k0){
    #pragma unroll
    for(int i=0;i<4;i++){
      int slot = (w*4+i)*64 + lane;
      int c = slot >> 7, r = slot & 127;
      gld16(A  + (size_t)(bm + r)*1024 + k0 + c*8, buf + (w*4+i)*512);
      gld16(Bt + (size_t)(bn + r)*1024 + k0 + c*8, buf + 8192 + (w*4+i)*512);
    }
  };
  auto compute = [&](const u16* buf){
    const u16* Al = buf; const u16* Bl = buf + 8192;
    bf16x8 af[4][2], bfv[4][2];
    #pragma unroll
    for(int mt=0;mt<4;mt++)
      #pragma unroll
      for(int kc=0;kc<2;kc++)
        af[mt][kc] = *(const bf16x8*)(Al + (((kc*4+quad)*128) + wm + mt*16 + cl)*8);
    #pragma unroll
    for(int nt=0;nt<4;nt++)
      #pragma unroll
      for(int kc=0;kc<2;kc++)
        bfv[nt][kc] = *(const bf16x8*)(Bl + (((kc*4+quad)*128) + wn + nt*16 + cl)*8);
    #pragma unroll
    for(int mt=0;mt<4;mt++)
      #pragma unroll
      for(int nt=0;nt<4;nt++)
        #pragma unroll
        for(int kc=0;kc<2;kc++)
          acc[mt][nt] = MFMA(af[mt][kc], bfv[nt][kc], acc[mt][nt]);
  };

  stage(b0, 0);
  #pragma unroll 1
  for(int it=0; it<16; it+=2){
    __syncthreads();
    if(it+1 < 16) stage(b1, (it+1)*64);
    compute(b0);
    __syncthreads();
    if(it+2 < 16) stage(b0, (it+2)*64);
    compute(b1);
  }
  #pragma unroll
  for(int mt=0;mt<4;mt++)
    #pragma unroll
    for(int nt=0;nt<4;nt++)
      #pragma unroll
      for(int i=0;i<4;i++){
        int m = bm + wm + mt*16 + quad*4 + i;
        int n = bn + wn + nt*16 + cl;
        Cf[(size_t)m*1024 + n] = acc[mt][nt][i];
      }
}

// ---------------- attention (vis): 8 waves x 16 q-rows; grid x=bh (XCD-grouped K/V) ----------------
__global__ __launch_bounds__(512, 4)
void attn_vis_kernel(const u16* __restrict__ Q, const u16* __restrict__ Kc,
                     const u16* __restrict__ Vt, u16* __restrict__ visA,
                     float* __restrict__ rl_g)
{
  __shared__ u16 lds[17408];   // 34816 B
  u16* Pl  = lds;              // P[q=128][72]; Q staged here first ([c8][128][8]=8192)
  u16* Kst = lds + 9216;       // [c8][64][8] = 4096 u16
  u16* Vst = lds + 13312;      // [d=64][ch^][8] swizzled = 4096 u16
  const int tid = threadIdx.x, w = tid>>6, lane = tid&63;
  const int quad = lane>>4, cl = lane&15;
  const int bh = blockIdx.x, q0 = blockIdx.y*128;   // XCD = bh % 8
  const u16* Qh  = Q  + (size_t)bh*65536;
  const u16* Kh  = Kc + (size_t)bh*65536;
  const u16* Vth = Vt + (size_t)bh*65536;

  #pragma unroll
  for(int i=0;i<2;i++){
    int slot = i*512 + tid;
    int c = slot >> 7, r = slot & 127;
    gld16(Qh + (size_t)(q0 + r)*64 + c*8, Pl + slot*8);
  }
  __syncthreads();
  bf16x8 qf[2];
  #pragma unroll
  for(int kk=0;kk<2;kk++)
    qf[kk] = *(const bf16x8*)(Pl + ((kk*4+quad)*128 + w*16 + cl)*8);
  __syncthreads();   // Pl now becomes the P buffer

  float lrun = 0.f;
  f32x4 oacc[4];
  #pragma unroll
  for(int dt=0;dt<4;dt++){ f32x4 z = {0.f,0.f,0.f,0.f}; oacc[dt] = z; }

  for(int kt=0;kt<16;kt++){
    __syncthreads();
    {
      int slot = tid;
      { int c = slot >> 6, r = slot & 63;
        gld16(Kh + (size_t)(kt*64 + r)*64 + c*8, Kst + slot*8); }
      { int d = slot >> 3, ch = slot & 7;
        gld16(Vth + (size_t)d*1024 + kt*64 + (ch^(d&7))*8, Vst + slot*8); }
    }
    __syncthreads();
    #pragma unroll
    for(int mtk=0;mtk<4;mtk++){
      f32x4 s = {0.f,0.f,0.f,0.f};
      #pragma unroll
      for(int kk=0;kk<2;kk++){
        bf16x8 ka = *(const bf16x8*)(Kst + ((kk*4+quad)*64 + mtk*16 + cl)*8);
        s = MFMA(ka, qf[kk], s);
      }
      float p0 = __builtin_amdgcn_exp2f(s[0]*LOG2E);
      float p1 = __builtin_amdgcn_exp2f(s[1]*LOG2E);
      float p2 = __builtin_amdgcn_exp2f(s[2]*LOG2E);
      float p3 = __builtin_amdgcn_exp2f(s[3]*LOG2E);
      lrun += (p0+p1)+(p2+p3);
      *(u16x4*)(Pl + (w*16 + cl)*72 + mtk*16 + quad*4) = pk4(p0,p1,p2,p3);
    }
    bf16x8 pa[2];
    #pragma unroll
    for(int kk=0;kk<2;kk++)
      pa[kk] = *(const bf16x8*)(Pl + (w*16 + cl)*72 + kk*32 + quad*8);
    #pragma unroll
    for(int dt=0;dt<4;dt++){
      int d = dt*16 + cl;
      #pragma unroll
      for(int kk=0;kk<2;kk++){
        bf16x8 vb = *(const bf16x8*)(Vst + d*64 + (((kk*4+quad)^(d&7))*8));
        oacc[dt] = MFMA(pa[kk], vb, oacc[dt]);
      }
    }
  }
  lrun += __shfl_xor(lrun, 16, 64);
  lrun += __shfl_xor(lrun, 32, 64);
  float rl = 1.f/lrun;
  if(quad == 0) rl_g[bh*1024 + q0 + w*16 + cl] = rl;
  const int b = bh >> 4, h = bh & 15;
  #pragma unroll
  for(int i=0;i<4;i++){
    float rr = __shfl(rl, quad*4 + i, 16);
    int q = q0 + w*16 + quad*4 + i;
    #pragma unroll
    for(int dt=0;dt<4;dt++)
      visA[(size_t)(b*1024 + q)*1024 + h*64 + dt*16 + cl] = f2bf(oacc[dt][i]*rr);
  }
}

// ---------------- attention (txt): 8 waves x 16 k-rows; grid x=bh; rl applied in-kernel ----------
__global__ __launch_bounds__(512, 4)
void attn_txt_kernel(const u16* __restrict__ Kc, const u16* __restrict__ Q,
                     const u16* __restrict__ V2t, const float* __restrict__ rl_g,
                     u16* __restrict__ txtA)
{
  __shared__ u16 lds[17408];
  u16* Pl  = lds;              // P^T[k=128][72]; K-block staged here first
  u16* Qst = lds + 9216;       // [c8][64][8]
  u16* Vst = lds + 13312;      // [d][ch^][8] swizzled (contraction = q)
  const int tid = threadIdx.x, w = tid>>6, lane = tid&63;
  const int quad = lane>>4, cl = lane&15;
  const int bh = blockIdx.x, k0 = blockIdx.y*128;   // XCD = bh % 8
  const u16* Kh  = Kc  + (size_t)bh*65536;
  const u16* Qh  = Q   + (size_t)bh*65536;
  const u16* Vth = V2t + (size_t)bh*65536;

  #pragma unroll
  for(int i=0;i<2;i++){
    int slot = i*512 + tid;
    int c = slot >> 7, r = slot & 127;
    gld16(Kh + (size_t)(k0 + r)*64 + c*8, Pl + slot*8);
  }
  __syncthreads();
  bf16x8 kb[2];
  #pragma unroll
  for(int kk=0;kk<2;kk++)
    kb[kk] = *(const bf16x8*)(Pl + ((kk*4+quad)*128 + w*16 + cl)*8);
  __syncthreads();

  f32x4 oacc[4];
  #pragma unroll
  for(int dt=0;dt<4;dt++){ f32x4 z = {0.f,0.f,0.f,0.f}; oacc[dt] = z; }

  for(int qt=0;qt<16;qt++){
    __syncthreads();
    {
      int slot = tid;
      { int c = slot >> 6, r = slot & 63;
        gld16(Qh + (size_t)(qt*64 + r)*64 + c*8, Qst + slot*8); }
      { int d = slot >> 3, ch = slot & 7;
        gld16(Vth + (size_t)d*1024 + qt*64 + (ch^(d&7))*8, Vst + slot*8); }
    }
    __syncthreads();
    f32x4 rv[4];
    #pragma unroll
    for(int mtq=0;mtq<4;mtq++)
      rv[mtq] = *(const f32x4*)(rl_g + bh*1024 + qt*64 + mtq*16 + quad*4);
    #pragma unroll
    for(int mtq=0;mtq<4;mtq++){
      f32x4 s = {0.f,0.f,0.f,0.f};
      #pragma unroll
      for(int kk=0;kk<2;kk++){
        bf16x8 qa = *(const bf16x8*)(Qst + ((kk*4+quad)*64 + mtq*16 + cl)*8);
        s = MFMA(qa, kb[kk], s);
      }
      float p0 = __builtin_amdgcn_exp2f(s[0]*LOG2E)*rv[mtq][0];
      float p1 = __builtin_amdgcn_exp2f(s[1]*LOG2E)*rv[mtq][1];
      float p2 = __builtin_amdgcn_exp2f(s[2]*LOG2E)*rv[mtq][2];
      float p3 = __builtin_amdgcn_exp2f(s[3]*LOG2E)*rv[mtq][3];
      *(u16x4*)(Pl + (w*16 + cl)*72 + mtq*16 + quad*4) = pk4(p0,p1,p2,p3);
    }
    bf16x8 pa[2];
    #pragma unroll
    for(int kk=0;kk<2;kk++)
      pa[kk] = *(const bf16x8*)(Pl + (w*16 + cl)*72 + kk*32 + quad*8);
    #pragma unroll
    for(int dt=0;dt<4;dt++){
      int d = dt*16 + cl;
      #pragma unroll
      for(int kk=0;kk<2;kk++){
        bf16x8 vb = *(const bf16x8*)(Vst + d*64 + (((kk*4+quad)^(d&7))*8));
        oacc[dt] = MFMA(pa[kk], vb, oacc[dt]);
      }
    }
  }
  const int b = bh >> 4, h = bh & 15;
  #pragma unroll
  for(int i=0;i<4;i++){
    int k = k0 + w*16 + quad*4 + i;
    #pragma unroll
    for(int dt=0;dt<4;dt++)
      txtA[(size_t)(b*1024 + k)*1024 + h*64 + dt*16 + cl] = f2bf(oacc[dt][i]);
  }
}

extern "C" void kernel_launch(void* const* d_in, const int* in_sizes, int n_in,
                              void* d_out, int out_size, void* d_ws, size_t ws_size,
                              hipStream_t stream)
{
  const float* vis = (const float*)d_in[0];
  const float* txt = (const float*)d_in[1];
  const float* Wq  = (const float*)d_in[2];
  const float* Wk  = (const float*)d_in[3];
  const float* Wv  = (const float*)d_in[4];
  const float* Wo  = (const float*)d_in[5];
  float* out = (float*)d_out;

  char* ws = (char*)d_ws;
  const size_t MB = 1u << 20;
  u16* vis16 = (u16*)(ws + 0);           // later: visA
  u16* txt16 = (u16*)(ws + 8*MB);        // later: txtA (contiguous with visA for out GEMM)
  u16* Wvis  = (u16*)(ws + 16*MB);       // [WqT | WvT]
  u16* Wtxt  = (u16*)(ws + 20*MB);       // [WkT | WvT]
  u16* Qb    = (u16*)(ws + 24*MB);
  u16* Kb    = (u16*)(ws + 32*MB);
  u16* Vt    = (u16*)(ws + 40*MB);       // V^T  [b][h][d][s]  (from txt proj)
  u16* V2t   = (u16*)(ws + 48*MB);       // V2^T [b][h][d][s]  (from vis proj)
  float* rl_g = (float*)(ws + 56*MB);
  u16* WoT   = (u16*)(ws + 57*MB);
  u16* visA = vis16;  u16* txtA = txt16;

  // 1: cast both inputs + 5 weight transposes
  prep_kernel<<<9472, 256, 0, stream>>>(vis, vis16, txt, txt16,
                                        Wq, Wk, Wv, Wo,
                                        Wvis, Wvis + 1048576, Wtxt, Wtxt + 1048576, WoT);
  // 2: merged projections, double-buffered; V/V2 written pre-transposed
  proj_gemm_kernel<<<dim3(16,32,2), 256, 0, stream>>>(vis16, txt16, Wvis, Wtxt,
                                                      Qb, V2t, Kb, Vt);
  // 3: attention vis (produces rl); visA overwrites vis16 (dead after projections)
  attn_vis_kernel<<<dim3(64,8), 512, 0, stream>>>(Qb, Kb, Vt, visA, rl_g);
  // 4: attention txt (applies rl in-kernel); txtA overwrites txt16
  attn_txt_kernel<<<dim3(64,8), 512, 0, stream>>>(Kb, Qb, V2t, rl_g, txtA);
  // 5: merged output projection, double-buffered: M=8192 over visA||txtA, f32 out
  out_gemm_kernel<<<dim3(8,64), 256, 0, stream>>>(visA, WoT, out);
}